// Round 11
// baseline (176.524 us; speedup 1.0000x reference)
//
#include <hip/hip_runtime.h>
#include <hip/hip_bf16.h>

#define N_DIM 8192
#define D_DIM 512
#define BM 128
#define BN 128
#define BK 64
#define NTILES 2080   // 64*65/2 upper-triangular 128x128 tiles

typedef float f32x4 __attribute__((ext_vector_type(4)));
typedef short bf16x8 __attribute__((ext_vector_type(8)));
typedef unsigned int u32;

// ---------------------------------------------------------------------------
// Kernel 1: L2-normalize rows of featureMatrix -> bf16 f in workspace.
// ---------------------------------------------------------------------------
__global__ __launch_bounds__(256) void normalize_rows_k(
    const float* __restrict__ feat, __hip_bfloat16* __restrict__ fb)
{
    const int w    = threadIdx.x >> 6;
    const int lane = threadIdx.x & 63;
    const int row  = blockIdx.x * 4 + w;

    const float* src = feat + (size_t)row * D_DIM + lane * 8;
    float4 v0 = *reinterpret_cast<const float4*>(src);
    float4 v1 = *reinterpret_cast<const float4*>(src + 4);

    float ss = v0.x*v0.x + v0.y*v0.y + v0.z*v0.z + v0.w*v0.w
             + v1.x*v1.x + v1.y*v1.y + v1.z*v1.z + v1.w*v1.w;
    #pragma unroll
    for (int off = 32; off; off >>= 1) ss += __shfl_xor(ss, off);

    const float r = 1.0f / fmaxf(sqrtf(ss), 1e-12f);

    union { ushort u[8]; uint4 q; } pk;
    float vals[8] = { v0.x, v0.y, v0.z, v0.w, v1.x, v1.y, v1.z, v1.w };
    #pragma unroll
    for (int i = 0; i < 8; ++i) {
        __hip_bfloat16 b = __float2bfloat16(vals[i] * r);
        pk.u[i] = *reinterpret_cast<ushort*>(&b);
    }
    *reinterpret_cast<uint4*>(fb + (size_t)row * D_DIM + lane * 8) = pk.q;
}

// ---------------------------------------------------------------------------
// Kernel 2: symmetric fused GEMM + masked MSE  (round-5 structure — best).
// Upper-triangular tiles only; off-diag blocks score both orig(br,bc) and
// orig(bc,br) [mirror read, contiguous float4] against the same accumulator.
//
// T2: fb tiles XOR-swizzled (byte ^= (row&7)<<4); gload_lds writes linearly,
// source address carries the inverse permutation (rule #21).
// LDS = exactly 32 KiB (no red[] — per-WAVE partials) -> 5 blocks/CU.
// __launch_bounds__(256,5): occupancy is the one measured positive lever.
// ---------------------------------------------------------------------------
__global__ __launch_bounds__(256, 5) void fused_gemm_loss_k(
    const __hip_bfloat16* __restrict__ fb,
    const float* __restrict__ orig,
    float* __restrict__ partials)
{
    __shared__ __align__(16) __hip_bfloat16 As[BM * BK];   // 16 KiB
    __shared__ __align__(16) __hip_bfloat16 Bs[BN * BK];   // 16 KiB

    // map bid -> upper-triangular (br, bc)
    int b = blockIdx.x, br = 0;
    while (b >= 64 - br) { b -= 64 - br; ++br; }
    const int bc  = br + b;
    const int tr0 = br * BM;
    const int tc0 = bc * BN;

    const int tid  = threadIdx.x;
    const int w    = tid >> 6;
    const int lane = tid & 63;
    const int wr   = w >> 1;        // 0..1
    const int wc   = w & 1;         // 0..1
    const int fr   = lane & 15;
    const int rsub = (lane >> 4) * 4;

    f32x4 acc[4][4] = {};

    // fb staging: 16 chunks of 1 KiB; chunk c covers LDS rows c*8..c*8+8.
    // Lane dest byte (linear) = c*1024 + lane*16 -> row c*8+(lane>>3),
    // within-row bits4-6 = lane&7.  Source col pre-swizzled: ^ (lane>>3).
    const int srow  = lane >> 3;                         // row within chunk
    const int scols = (((lane & 7) ^ (lane >> 3)) * 8);  // swizzled col elem

    for (int k0 = 0; k0 < D_DIM; k0 += BK) {
        #pragma unroll
        for (int t = 0; t < 4; ++t) {
            const int c = w * 4 + t;
            const int rowA = tr0 + c * 8 + srow;
            const int rowB = tc0 + c * 8 + srow;
            const __hip_bfloat16* gA = fb + (size_t)rowA * D_DIM + k0 + scols;
            const __hip_bfloat16* gB = fb + (size_t)rowB * D_DIM + k0 + scols;
            __builtin_amdgcn_global_load_lds(
                (const __attribute__((address_space(1))) u32*)gA,
                (__attribute__((address_space(3))) u32*)(As + c * 512),
                16, 0, 0);
            __builtin_amdgcn_global_load_lds(
                (const __attribute__((address_space(1))) u32*)gB,
                (__attribute__((address_space(3))) u32*)(Bs + c * 512),
                16, 0, 0);
        }
        __syncthreads();

        const int krow = lane >> 4;
        const int sw   = (fr & 7) << 4;                  // read-side swizzle
        #pragma unroll
        for (int kk = 0; kk < BK; kk += 32) {
            bf16x8 af[4], bfr[4];
            #pragma unroll
            for (int fm = 0; fm < 4; ++fm) {
                const int r = wr * 64 + fm * 16 + fr;
                af[fm] = *reinterpret_cast<const bf16x8*>(
                    (const char*)As + r * 128 + (((kk << 1) + (krow << 4)) ^ sw));
            }
            #pragma unroll
            for (int fn = 0; fn < 4; ++fn) {
                const int r = wc * 64 + fn * 16 + fr;
                bfr[fn] = *reinterpret_cast<const bf16x8*>(
                    (const char*)Bs + r * 128 + (((kk << 1) + (krow << 4)) ^ sw));
            }
            #pragma unroll
            for (int fm = 0; fm < 4; ++fm)
                #pragma unroll
                for (int fn = 0; fn < 4; ++fn)
                    acc[fm][fn] = __builtin_amdgcn_mfma_f32_16x16x32_bf16(
                        af[fm], bfr[fn], acc[fm][fn], 0, 0, 0);
        }
        __syncthreads();
    }

    // ---- fused masked-MSE epilogue (direct global reads, TLP-hidden) ----
    // C/D layout: col = lane&15, row = (lane>>4)*4 + v
    float lsum = 0.0f, lcnt = 0.0f;

    // normal tile (br, bc): per-row scalar reads (16-lane coalesced)
    #pragma unroll
    for (int fm = 0; fm < 4; ++fm) {
        #pragma unroll
        for (int v = 0; v < 4; ++v) {
            const int row = tr0 + wr * 64 + fm * 16 + rsub + v;
            const float* orow = orig + (size_t)row * N_DIM + tc0 + wc * 64;
            #pragma unroll
            for (int fn = 0; fn < 4; ++fn) {
                const float o = orow[fn * 16 + fr];
                if (o != 0.0f) {
                    const float d = o - acc[fm][fn][v];
                    lsum += d * d;
                    lcnt += 1.0f;
                }
            }
        }
    }

    // mirror tile (bc, br): orig[col][row..row+3] contiguous -> float4
    if (br != bc) {
        #pragma unroll
        for (int fm = 0; fm < 4; ++fm) {
            const int rbase = tr0 + wr * 64 + fm * 16 + rsub;
            #pragma unroll
            for (int fn = 0; fn < 4; ++fn) {
                const int col = tc0 + wc * 64 + fn * 16 + fr;
                const float4 o4 = *reinterpret_cast<const float4*>(
                    orig + (size_t)col * N_DIM + rbase);
                const float ov[4] = { o4.x, o4.y, o4.z, o4.w };
                #pragma unroll
                for (int v = 0; v < 4; ++v) {
                    if (ov[v] != 0.0f) {
                        const float d = ov[v] - acc[fm][fn][v];
                        lsum += d * d;
                        lcnt += 1.0f;
                    }
                }
            }
        }
    }

    #pragma unroll
    for (int off = 32; off; off >>= 1) {
        lsum += __shfl_xor(lsum, off);
        lcnt += __shfl_xor(lcnt, off);
    }
    // per-WAVE partials (no LDS reduce, no extra barrier): 4 pairs per block
    if (lane == 0) {
        const size_t idx = (size_t)blockIdx.x * 4 + w;
        partials[idx * 2]     = lsum;
        partials[idx * 2 + 1] = lcnt;
    }
}

// ---------------------------------------------------------------------------
// Kernel 3: deterministic reduce of per-wave partials -> out[0] = sum/count
// (8320 pairs; 1024 threads, ~8 strided passes + 16-wave tree)
// ---------------------------------------------------------------------------
__global__ __launch_bounds__(1024) void final_reduce_k(
    const float* __restrict__ partials, float* __restrict__ out, int np)
{
    __shared__ float rs[16], rc[16];
    float s = 0.0f, c = 0.0f;
    for (int i = threadIdx.x; i < np; i += 1024) {
        s += partials[(size_t)i * 2];
        c += partials[(size_t)i * 2 + 1];
    }
    #pragma unroll
    for (int off = 32; off; off >>= 1) {
        s += __shfl_xor(s, off);
        c += __shfl_xor(c, off);
    }
    const int w = threadIdx.x >> 6, lane = threadIdx.x & 63;
    if (lane == 0) { rs[w] = s; rc[w] = c; }
    __syncthreads();
    if (threadIdx.x == 0) {
        float S = 0.0f, C = 0.0f;
        #pragma unroll
        for (int i = 0; i < 16; ++i) { S += rs[i]; C += rc[i]; }
        out[0] = S / C;
    }
}

// ---------------------------------------------------------------------------
extern "C" void kernel_launch(void* const* d_in, const int* in_sizes, int n_in,
                              void* d_out, int out_size, void* d_ws, size_t ws_size,
                              hipStream_t stream)
{
    const float* orig = (const float*)d_in[0];   // originalMatrix [N,N]
    const float* feat = (const float*)d_in[1];   // featureMatrix  [N,D]
    float* out = (float*)d_out;

    __hip_bfloat16* fb = (__hip_bfloat16*)d_ws;                       // 8 MiB
    float* partials = (float*)((char*)d_ws + (size_t)N_DIM * D_DIM * 2);

    normalize_rows_k<<<N_DIM / 4, 256, 0, stream>>>(feat, fb);
    fused_gemm_loss_k<<<NTILES, 256, 0, stream>>>(fb, orig, partials);
    final_reduce_k<<<1, 1024, 0, stream>>>(partials, out, NTILES * 4);
}

// Round 12
// 88.133 us; speedup vs baseline: 2.0029x; 2.0029x over previous
//
#include <hip/hip_runtime.h>
#include <hip/hip_bf16.h>

#define N_DIM 8192
#define D_DIM 512
#define BM 128
#define BN 128
#define BK 64
#define NTILES 2080   // 64*65/2 upper-triangular 128x128 tiles

typedef float f32x4 __attribute__((ext_vector_type(4)));
typedef short bf16x8 __attribute__((ext_vector_type(8)));
typedef unsigned int u32;

// ---------------------------------------------------------------------------
// Kernel 1: L2-normalize rows of featureMatrix -> bf16 f in workspace.
// ---------------------------------------------------------------------------
__global__ __launch_bounds__(256) void normalize_rows_k(
    const float* __restrict__ feat, __hip_bfloat16* __restrict__ fb)
{
    const int w    = threadIdx.x >> 6;
    const int lane = threadIdx.x & 63;
    const int row  = blockIdx.x * 4 + w;

    const float* src = feat + (size_t)row * D_DIM + lane * 8;
    float4 v0 = *reinterpret_cast<const float4*>(src);
    float4 v1 = *reinterpret_cast<const float4*>(src + 4);

    float ss = v0.x*v0.x + v0.y*v0.y + v0.z*v0.z + v0.w*v0.w
             + v1.x*v1.x + v1.y*v1.y + v1.z*v1.z + v1.w*v1.w;
    #pragma unroll
    for (int off = 32; off; off >>= 1) ss += __shfl_xor(ss, off);

    const float r = 1.0f / fmaxf(sqrtf(ss), 1e-12f);

    union { ushort u[8]; uint4 q; } pk;
    float vals[8] = { v0.x, v0.y, v0.z, v0.w, v1.x, v1.y, v1.z, v1.w };
    #pragma unroll
    for (int i = 0; i < 8; ++i) {
        __hip_bfloat16 b = __float2bfloat16(vals[i] * r);
        pk.u[i] = *reinterpret_cast<ushort*>(&b);
    }
    *reinterpret_cast<uint4*>(fb + (size_t)row * D_DIM + lane * 8) = pk.q;
}

// ---------------------------------------------------------------------------
// Kernel 2: symmetric fused GEMM + masked MSE  (round-5 configuration —
// the measured optimum of this session; every structural deviation
// regressed: R3/R4 DMA epilogue, R6 2-phase, R7 XCD swizzle, R8 LDS-free,
// R9 nt-hints, R11 occupancy-5/VGPR-spill).
//
// Upper-triangular tiles only; off-diag blocks score both orig(br,bc) and
// orig(bc,br) [mirror read, contiguous float4] against the same accumulator.
// T2: fb tiles XOR-swizzled (byte ^= (row&7)<<4); gload_lds writes linearly,
// source address carries the inverse permutation (rule #21).
// LDS 32.3 KB + VGPR 104 -> 4 blocks/CU (the measured VGPR wall: 5 blocks
// forces <=102 regs -> accumulator spill, +99% dur — R11).
// ---------------------------------------------------------------------------
__global__ __launch_bounds__(256, 3) void fused_gemm_loss_k(
    const __hip_bfloat16* __restrict__ fb,
    const float* __restrict__ orig,
    float* __restrict__ partials)
{
    __shared__ __align__(16) __hip_bfloat16 As[BM * BK];
    __shared__ __align__(16) __hip_bfloat16 Bs[BN * BK];
    __shared__ float red[8];

    // map bid -> upper-triangular (br, bc)
    int b = blockIdx.x, br = 0;
    while (b >= 64 - br) { b -= 64 - br; ++br; }
    const int bc  = br + b;
    const int tr0 = br * BM;
    const int tc0 = bc * BN;

    const int tid  = threadIdx.x;
    const int w    = tid >> 6;
    const int lane = tid & 63;
    const int wr   = w >> 1;        // 0..1
    const int wc   = w & 1;         // 0..1
    const int fr   = lane & 15;
    const int rsub = (lane >> 4) * 4;

    f32x4 acc[4][4] = {};

    // fb staging: 16 chunks of 1 KiB; chunk c covers LDS rows c*8..c*8+8.
    // Lane dest byte (linear) = c*1024 + lane*16 -> row c*8+(lane>>3),
    // within-row bits4-6 = lane&7.  Source col pre-swizzled: ^ (lane>>3).
    const int srow  = lane >> 3;                         // row within chunk
    const int scols = (((lane & 7) ^ (lane >> 3)) * 8);  // swizzled col elem

    for (int k0 = 0; k0 < D_DIM; k0 += BK) {
        #pragma unroll
        for (int t = 0; t < 4; ++t) {
            const int c = w * 4 + t;
            const int rowA = tr0 + c * 8 + srow;
            const int rowB = tc0 + c * 8 + srow;
            const __hip_bfloat16* gA = fb + (size_t)rowA * D_DIM + k0 + scols;
            const __hip_bfloat16* gB = fb + (size_t)rowB * D_DIM + k0 + scols;
            __builtin_amdgcn_global_load_lds(
                (const __attribute__((address_space(1))) u32*)gA,
                (__attribute__((address_space(3))) u32*)(As + c * 512),
                16, 0, 0);
            __builtin_amdgcn_global_load_lds(
                (const __attribute__((address_space(1))) u32*)gB,
                (__attribute__((address_space(3))) u32*)(Bs + c * 512),
                16, 0, 0);
        }
        __syncthreads();

        const int krow = lane >> 4;
        const int sw   = (fr & 7) << 4;                  // read-side swizzle
        #pragma unroll
        for (int kk = 0; kk < BK; kk += 32) {
            bf16x8 af[4], bfr[4];
            #pragma unroll
            for (int fm = 0; fm < 4; ++fm) {
                const int r = wr * 64 + fm * 16 + fr;
                af[fm] = *reinterpret_cast<const bf16x8*>(
                    (const char*)As + r * 128 + (((kk << 1) + (krow << 4)) ^ sw));
            }
            #pragma unroll
            for (int fn = 0; fn < 4; ++fn) {
                const int r = wc * 64 + fn * 16 + fr;
                bfr[fn] = *reinterpret_cast<const bf16x8*>(
                    (const char*)Bs + r * 128 + (((kk << 1) + (krow << 4)) ^ sw));
            }
            #pragma unroll
            for (int fm = 0; fm < 4; ++fm)
                #pragma unroll
                for (int fn = 0; fn < 4; ++fn)
                    acc[fm][fn] = __builtin_amdgcn_mfma_f32_16x16x32_bf16(
                        af[fm], bfr[fn], acc[fm][fn], 0, 0, 0);
        }
        __syncthreads();
    }

    // ---- fused masked-MSE epilogue (direct global reads, TLP-hidden) ----
    // C/D layout: col = lane&15, row = (lane>>4)*4 + v
    float lsum = 0.0f, lcnt = 0.0f;

    // normal tile (br, bc): per-row scalar reads (16-lane coalesced)
    #pragma unroll
    for (int fm = 0; fm < 4; ++fm) {
        #pragma unroll
        for (int v = 0; v < 4; ++v) {
            const int row = tr0 + wr * 64 + fm * 16 + rsub + v;
            const float* orow = orig + (size_t)row * N_DIM + tc0 + wc * 64;
            #pragma unroll
            for (int fn = 0; fn < 4; ++fn) {
                const float o = orow[fn * 16 + fr];
                if (o != 0.0f) {
                    const float d = o - acc[fm][fn][v];
                    lsum += d * d;
                    lcnt += 1.0f;
                }
            }
        }
    }

    // mirror tile (bc, br): orig[col][row..row+3] contiguous -> float4
    if (br != bc) {
        #pragma unroll
        for (int fm = 0; fm < 4; ++fm) {
            const int rbase = tr0 + wr * 64 + fm * 16 + rsub;
            #pragma unroll
            for (int fn = 0; fn < 4; ++fn) {
                const int col = tc0 + wc * 64 + fn * 16 + fr;
                const float4 o4 = *reinterpret_cast<const float4*>(
                    orig + (size_t)col * N_DIM + rbase);
                const float ov[4] = { o4.x, o4.y, o4.z, o4.w };
                #pragma unroll
                for (int v = 0; v < 4; ++v) {
                    if (ov[v] != 0.0f) {
                        const float d = ov[v] - acc[fm][fn][v];
                        lsum += d * d;
                        lcnt += 1.0f;
                    }
                }
            }
        }
    }

    #pragma unroll
    for (int off = 32; off; off >>= 1) {
        lsum += __shfl_xor(lsum, off);
        lcnt += __shfl_xor(lcnt, off);
    }
    if (lane == 0) { red[w * 2] = lsum; red[w * 2 + 1] = lcnt; }
    __syncthreads();
    if (tid == 0) {
        float s = 0.0f, c = 0.0f;
        #pragma unroll
        for (int i = 0; i < 4; ++i) { s += red[i * 2]; c += red[i * 2 + 1]; }
        partials[(size_t)blockIdx.x * 2]     = s;
        partials[(size_t)blockIdx.x * 2 + 1] = c;
    }
}

// ---------------------------------------------------------------------------
// Kernel 3: deterministic reduce of per-block partials -> out[0] = sum/count
// ---------------------------------------------------------------------------
__global__ __launch_bounds__(256) void final_reduce_k(
    const float* __restrict__ partials, float* __restrict__ out, int nb)
{
    __shared__ float rs[4], rc[4];
    float s = 0.0f, c = 0.0f;
    for (int i = threadIdx.x; i < nb; i += 256) {
        s += partials[(size_t)i * 2];
        c += partials[(size_t)i * 2 + 1];
    }
    #pragma unroll
    for (int off = 32; off; off >>= 1) {
        s += __shfl_xor(s, off);
        c += __shfl_xor(c, off);
    }
    const int w = threadIdx.x >> 6, lane = threadIdx.x & 63;
    if (lane == 0) { rs[w] = s; rc[w] = c; }
    __syncthreads();
    if (threadIdx.x == 0) {
        const float S = rs[0] + rs[1] + rs[2] + rs[3];
        const float C = rc[0] + rc[1] + rc[2] + rc[3];
        out[0] = S / C;
    }
}

// ---------------------------------------------------------------------------
extern "C" void kernel_launch(void* const* d_in, const int* in_sizes, int n_in,
                              void* d_out, int out_size, void* d_ws, size_t ws_size,
                              hipStream_t stream)
{
    const float* orig = (const float*)d_in[0];   // originalMatrix [N,N]
    const float* feat = (const float*)d_in[1];   // featureMatrix  [N,D]
    float* out = (float*)d_out;

    __hip_bfloat16* fb = (__hip_bfloat16*)d_ws;                       // 8 MiB
    float* partials = (float*)((char*)d_ws + (size_t)N_DIM * D_DIM * 2);

    normalize_rows_k<<<N_DIM / 4, 256, 0, stream>>>(feat, fb);
    fused_gemm_loss_k<<<NTILES, 256, 0, stream>>>(fb, orig, partials);
    final_reduce_k<<<1, 256, 0, stream>>>(partials, out, NTILES);
}